// Round 6
// baseline (171.884 us; speedup 1.0000x reference)
//
#include <hip/hip_runtime.h>
#include <math.h>

#define NB 4096
#define NC 3
#define ND 512
#define NBC (NB + NC)                 // 4099
#define ADJ ((size_t)NBC * (size_t)NBC)

static constexpr float HID = 0.5f / 1.5f;       // 0.5 / DELTA
static constexpr float RS3 = 0.57735026919f;    // 1/sqrt(3)

// ---- ws layout (float offsets) ---------------------------------------------
#define OFF_CNT  0                         // int counts[9] (pad 16)
#define OFF_CSUM 16                        // atomic center sums [3][3][ND]
#define OFF_ST   (OFF_CSUM + 9*ND)         // SoA stats [30][NB]  (j-side, coalesced)
#define OFF_AOS  (OFF_ST + 30*NB)          // AoS stats [NB][36]  (i-side, scalar)
// field k per modality m:
//   k=0: A = 0.5 - HID*sum p log p + HID*log p2
//   k=1: p0   k=2: p1
//   k=3: s1 = (pred>=1)   k=4: s2 = (pred>=2)
//   k=5: d0 = HID*(lp0-lp2)   k=6: d1 = HID*(lp1-lp2)
//   k=7: F0/sqrt3   k=8: (F1-F0)/sqrt3   k=9: (F2-F1)/sqrt3   (kD fills 7..9)

__device__ __forceinline__ float dot8(const float4& a, const float4& b,
                                      const float4& c, const float4& d) {
    return a.x*c.x + a.y*c.y + a.z*c.z + a.w*c.w +
           b.x*d.x + b.y*d.y + b.z*d.z + b.w*d.w;
}

__device__ __forceinline__ float wred(float v) {
    #pragma unroll
    for (int off = 32; off > 0; off >>= 1) v += __shfl_xor(v, off, 64);
    return v;
}

// ---- kAB: label stats (SoA+AoS) + per-block class sums via atomics ---------
__global__ void __launch_bounds__(256) kAB(const float* __restrict__ tf,
                                           const float* __restrict__ af,
                                           const float* __restrict__ vf,
                                           const float* __restrict__ tl,
                                           const float* __restrict__ al,
                                           const float* __restrict__ vl,
                                           float* __restrict__ ws) {
    __shared__ int spred[16][3];
    __shared__ int scnt[9];
    int t = threadIdx.x;
    if (t < 9) scnt[t] = 0;
    int r0 = blockIdx.x * 16;
    __syncthreads();
    if (t < 48) {
        int r = t / 3, m = t % 3;
        const float* labs[3] = {tl, al, vl};
        int i = r0 + r;
        float p0 = labs[m][i*3+0], p1 = labs[m][i*3+1], p2 = labs[m][i*3+2];
        float l0 = logf(p0), l1 = logf(p1), l2 = logf(p2);
        float A  = 0.5f - HID * (p0*l0 + p1*l1 + p2*l2) + HID*l2;
        int pred = 0; float pm = p0;
        if (p1 > pm) { pred = 1; pm = p1; }
        if (p2 > pm) { pred = 2; }
        float s1 = (pred >= 1) ? 1.0f : 0.0f;
        float s2 = (pred >= 2) ? 1.0f : 0.0f;
        float d0 = HID*(l0 - l2), d1 = HID*(l1 - l2);
        float* st = ws + OFF_ST + (size_t)(m*10)*NB + i;
        st[0*NB] = A;  st[1*NB] = p0; st[2*NB] = p1;
        st[3*NB] = s1; st[4*NB] = s2; st[5*NB] = d0; st[6*NB] = d1;
        float* ao = ws + OFF_AOS + (size_t)i*36 + m*12;
        ao[0] = A;  ao[1] = p0; ao[2] = p1; ao[3] = s1;
        ao[4] = s2; ao[5] = d0; ao[6] = d1;
        spred[r][m] = pred;
        atomicAdd(&scnt[m*3 + pred], 1);
    }
    __syncthreads();
    if (t < 9) atomicAdd((int*)ws + OFF_CNT + t, scnt[t]);

    const float* feats[3] = {tf, af, vf};
    float acc[3][3][2] = {};
    #pragma unroll
    for (int rr = 0; rr < 16; ++rr) {
        int i = r0 + rr;
        #pragma unroll
        for (int mm = 0; mm < 3; ++mm) {
            float z0 = feats[mm][(size_t)i*ND + t];
            float z1 = feats[mm][(size_t)i*ND + t + 256];
            int pr = spred[rr][mm];
            #pragma unroll
            for (int c = 0; c < 3; ++c) {
                acc[mm][c][0] += (pr == c) ? z0 : 0.0f;
                acc[mm][c][1] += (pr == c) ? z1 : 0.0f;
            }
        }
    }
    #pragma unroll
    for (int mm = 0; mm < 3; ++mm)
        #pragma unroll
        for (int c = 0; c < 3; ++c) {
            atomicAdd(&ws[OFF_CSUM + (mm*3+c)*ND + t],       acc[mm][c][0]);
            atomicAdd(&ws[OFF_CSUM + (mm*3+c)*ND + t + 256], acc[mm][c][1]);
        }
}

// ---- kD: F factors + fused border + node-feat rows + tail/eye --------------
__global__ void __launch_bounds__(256) kD(const float* __restrict__ tf,
                                          const float* __restrict__ af,
                                          const float* __restrict__ vf,
                                          const float* __restrict__ fused,
                                          const float* __restrict__ ccp,
                                          float* __restrict__ ws,
                                          float* __restrict__ out) {
    int wid = threadIdx.x >> 6, lane = threadIdx.x & 63;
    int i = blockIdx.x * 4 + wid;
    const float* feats[3] = {tf, af, vf};
    int d0 = lane * 8;

    const int* cnt = (const int*)ws + OFF_CNT;
    float inv[3][3];
    #pragma unroll
    for (int m = 0; m < 3; ++m)
        #pragma unroll
        for (int c = 0; c < 3; ++c)
            inv[m][c] = 1.0f / fmaxf((float)cnt[m*3+c], 1.0f);

    #pragma unroll
    for (int m = 0; m < 3; ++m) {
        const float4* z4 = (const float4*)(feats[m] + ((size_t)i << 9) + d0);
        float4 za = z4[0], zb = z4[1];
        float v0 = dot8(za, zb, za, zb);
        float vc[3], nc[3];
        #pragma unroll
        for (int c = 0; c < 3; ++c) {
            const float4* s4 = (const float4*)(ws + OFF_CSUM + (size_t)(m*3+c)*ND + d0);
            float4 ca = s4[0], cb = s4[1];
            float iv = inv[m][c];
            ca.x *= iv; ca.y *= iv; ca.z *= iv; ca.w *= iv;
            cb.x *= iv; cb.y *= iv; cb.z *= iv; cb.w *= iv;
            vc[c] = dot8(za, zb, ca, cb);
            nc[c] = dot8(ca, cb, ca, cb);
        }
        v0 = wred(v0);
        vc[0] = wred(vc[0]); vc[1] = wred(vc[1]); vc[2] = wred(vc[2]);
        nc[0] = wred(nc[0]); nc[1] = wred(nc[1]); nc[2] = wred(nc[2]);
        if (lane == 0) {
            float e0 = expf(vc[0] - 0.5f*(v0 + nc[0]));
            float e1 = expf(vc[1] - 0.5f*(v0 + nc[1]));
            float e2 = expf(vc[2] - 0.5f*(v0 + nc[2]));
            float F0 = e0 * RS3, DF1 = (e1 - e0) * RS3, DF2 = (e2 - e1) * RS3;
            float* st = ws + OFF_ST + (size_t)(m*10)*NB + i;
            st[7*NB] = F0; st[8*NB] = DF1; st[9*NB] = DF2;
            float* ao = ws + OFF_AOS + (size_t)i*36 + m*12;
            ao[7] = F0; ao[8] = DF1; ao[9] = DF2;
        }
    }

    // fused pseudo-label argmax + w_center (+ node-feature row store)
    const float4* f4 = (const float4*)(fused + ((size_t)i << 9) + d0);
    float4 fa = f4[0], fb = f4[1];
    // node_features rows 0..NB-1 (folded memcpy; ADJ is odd -> dword stores)
    float* nfr = out + ADJ + ((size_t)i << 9) + d0;
    nfr[0] = fa.x; nfr[1] = fa.y; nfr[2] = fa.z; nfr[3] = fa.w;
    nfr[4] = fb.x; nfr[5] = fb.y; nfr[6] = fb.z; nfr[7] = fb.w;

    const float4* p0 = (const float4*)(ccp + 0*ND + d0);
    const float4* p1 = (const float4*)(ccp + 1*ND + d0);
    const float4* p2 = (const float4*)(ccp + 2*ND + d0);
    float l0 = wred(dot8(fa, fb, p0[0], p0[1]));
    float l1 = wred(dot8(fa, fb, p1[0], p1[1]));
    float l2 = wred(dot8(fa, fb, p2[0], p2[1]));
    int pf = 0; float lm = l0;
    if (l1 > lm) { pf = 1; lm = l1; }
    if (l2 > lm) { pf = 2; }
    float4 aa = {0,0,0,0}, ab = {0,0,0,0};
    #pragma unroll
    for (int m = 0; m < 3; ++m) {
        const float4* s4 = (const float4*)(ws + OFF_CSUM + (size_t)(m*3+pf)*ND + d0);
        float4 ca = s4[0], cb = s4[1];
        float iv = inv[m][pf] * (1.0f/3.0f);
        aa.x = fmaf(ca.x, iv, aa.x); aa.y = fmaf(ca.y, iv, aa.y);
        aa.z = fmaf(ca.z, iv, aa.z); aa.w = fmaf(ca.w, iv, aa.w);
        ab.x = fmaf(cb.x, iv, ab.x); ab.y = fmaf(cb.y, iv, ab.y);
        ab.z = fmaf(cb.z, iv, ab.z); ab.w = fmaf(cb.w, iv, ab.w);
    }
    float dxx = fa.x-aa.x, dxy = fa.y-aa.y, dxz = fa.z-aa.z, dxw = fa.w-aa.w;
    float dyx = fb.x-ab.x, dyy = fb.y-ab.y, dyz = fb.z-ab.z, dyw = fb.w-ab.w;
    float dsq = wred(dxx*dxx + dxy*dxy + dxz*dxz + dxw*dxw +
                     dyx*dyx + dyy*dyy + dyz*dyz + dyw*dyw);
    if (lane == 0) {
        float wc = expf(-0.5f * dsq);
        #pragma unroll
        for (int c = 0; c < 3; ++c) {
            float v = (c == pf) ? wc : 0.0f;
            out[(size_t)i*NBC + NB + c]   = v;
            out[(size_t)(NB + c)*NBC + i] = v;
        }
    }

    // tail rows (blocks 0..2) + eye (block 0)
    if (blockIdx.x < 3) {
        int c = blockIdx.x;
        for (int d = threadIdx.x; d < ND; d += 256) {
            float av = 0.0f;
            #pragma unroll
            for (int m = 0; m < 3; ++m)
                av = fmaf(ws[OFF_CSUM + (size_t)(m*3+c)*ND + d],
                          inv[m][c] * (1.0f/3.0f), av);
            out[ADJ + (size_t)(NB + c)*ND + d] = av;
        }
        if (c == 0 && threadIdx.x < 9) {
            int rr = threadIdx.x / 3, cc = threadIdx.x % 3;
            out[(size_t)(NB + rr)*NBC + NB + cc] = (rr == cc) ? 1.0f : 0.0f;
        }
    }
}

// ---- kE: B x B block. 1024j x 64i tile, scalar i-side, no LDS --------------
__global__ void __launch_bounds__(256) kE(const float* __restrict__ ws,
                                          float* __restrict__ out) {
    int t = threadIdx.x;
    int jbase = blockIdx.x * 1024;
    int i0 = blockIdx.y * 64;
    const float* st  = ws + OFF_ST;
    const float* aos = ws + OFF_AOS;

    // j-side registers: J[m][k][q], j = jbase + q*256 + t  (coalesced SoA)
    float J[3][10][4];
    #pragma unroll
    for (int m = 0; m < 3; ++m)
        #pragma unroll
        for (int k = 0; k < 10; ++k) {
            const float* b = st + (size_t)(m * 10 + k) * NB + jbase + t;
            #pragma unroll
            for (int q = 0; q < 4; ++q) J[m][k][q] = b[q * 256];
        }

    float* p = out + (size_t)i0 * NBC + jbase + t;
    int jt = jbase + t;
    for (int r = 0; r < 64; ++r) {
        int i = __builtin_amdgcn_readfirstlane(i0 + r);   // force scalar path
        const float* row = aos + (size_t)i * 36;
        float acc0 = 0.0f, acc1 = 0.0f, acc2 = 0.0f, acc3 = 0.0f;
        #pragma unroll
        for (int m = 0; m < 3; ++m) {
            float4 Q1 = *(const float4*)(row + m * 12);      // A,p0,p1,s1
            float4 Q2 = *(const float4*)(row + m * 12 + 4);  // s2,d0,d1,F0
            float2 Q3 = *(const float2*)(row + m * 12 + 8);  // DF1,DF2
            float accq[4];
            #pragma unroll
            for (int q = 0; q < 4; ++q) {
                float tt = Q1.x + J[m][0][q];                // A_i + A_j
                tt = fmaf(Q1.y, J[m][5][q], tt);             // p0_i * d0_j
                tt = fmaf(Q1.z, J[m][6][q], tt);             // p1_i * d1_j
                tt = fmaf(J[m][1][q], Q2.y, tt);             // p0_j * d0_i
                tt = fmaf(J[m][2][q], Q2.z, tt);             // p1_j * d1_i
                tt = fmaxf(tt, 0.0f);
                float Fi = fmaf(J[m][4][q], Q3.y, fmaf(J[m][3][q], Q3.x, Q2.w));
                float Fj = fmaf(Q2.x, J[m][9][q], fmaf(Q1.w, J[m][8][q], J[m][7][q]));
                accq[q] = tt * (Fi * Fj);
            }
            acc0 += accq[0]; acc1 += accq[1]; acc2 += accq[2]; acc3 += accq[3];
        }
        int ii = i0 + r;
        float v0 = (ii == jt)        ? 0.0f : acc0;
        float v1 = (ii == jt + 256)  ? 0.0f : acc1;
        float v2 = (ii == jt + 512)  ? 0.0f : acc2;
        float v3 = (ii == jt + 768)  ? 0.0f : acc3;
        __builtin_nontemporal_store(v0, p);
        __builtin_nontemporal_store(v1, p + 256);
        __builtin_nontemporal_store(v2, p + 512);
        __builtin_nontemporal_store(v3, p + 768);
        p += NBC;
    }
}

extern "C" void kernel_launch(void* const* d_in, const int* in_sizes, int n_in,
                              void* d_out, int out_size, void* d_ws, size_t ws_size,
                              hipStream_t stream) {
    const float* tf    = (const float*)d_in[0];
    const float* af    = (const float*)d_in[1];
    const float* vf    = (const float*)d_in[2];
    const float* tl    = (const float*)d_in[3];
    const float* al    = (const float*)d_in[4];
    const float* vl    = (const float*)d_in[5];
    const float* fused = (const float*)d_in[6];
    const float* ccp   = (const float*)d_in[7];
    float* out = (float*)d_out;
    float* ws  = (float*)d_ws;

    hipMemsetAsync(ws, 0, (OFF_CSUM + 9*ND) * sizeof(float), stream);

    kAB<<<NB/16, 256, 0, stream>>>(tf, af, vf, tl, al, vl, ws);
    kD<<<NB/4, 256, 0, stream>>>(tf, af, vf, fused, ccp, ws, out);
    kE<<<dim3(NB/1024, NB/64), 256, 0, stream>>>(ws, out);
}